// Round 1
// baseline (956.372 us; speedup 1.0000x reference)
//
#include <hip/hip_runtime.h>
#include <math.h>

#define DM 64      // d_manifold
#define RF 64      // n_rff
#define STRENGTH 0.1f
#define SQRT_2_OVER_R 0.17677669529663687f   // sqrt(2/64)
#define NBATCH 8   // fixed by setup_inputs (flat sizes cannot separate B from T)

__device__ __forceinline__ float wave_reduce_sum(float v) {
    #pragma unroll
    for (int off = 32; off > 0; off >>= 1)
        v += __shfl_xor(v, off, 64);
    return v;
}

// Pass 1: per-token mass & phi; accumulate phi_sum[b][r] = sum_t phi*mass.
// One wave per token; lane index doubles as feature index i and RFF index r.
__global__ __launch_bounds__(256) void gravity_pass1(
        const float* __restrict__ coords,   // [B,T,D]
        const float* __restrict__ w1,       // [D,D]
        const float* __restrict__ b1,       // [D]
        const float* __restrict__ w2,       // [D] (shape (1,D))
        const float* __restrict__ b2,       // [1]
        const float* __restrict__ Wr,       // [D,R]
        const float* __restrict__ br,       // [R]
        float* __restrict__ phi_sum,        // [B,R] (pre-zeroed)
        int T) {
    const int lane = threadIdx.x & 63;
    const int wave = threadIdx.x >> 6;      // 0..3
    const int b    = blockIdx.y;
    const int wavesPerBatch = gridDim.x * 4;
    const int waveIdx = blockIdx.x * 4 + wave;

    float acc = 0.f;   // lane r's partial of phi_sum[b][r]

    for (int t = waveIdx; t < T; t += wavesPerBatch) {
        const float* cptr = coords + ((size_t)b * T + t) * DM;
        float c = cptr[lane];
        float h  = b1[lane];    // lane i: hidden pre-activation
        float pd = br[lane];    // lane r: RFF phase
        #pragma unroll
        for (int k = 0; k < DM; ++k) {
            float ck = __shfl(c, k, 64);
            h  = fmaf(ck, w1[lane * DM + k], h);
            pd = fmaf(ck, Wr[k * RF + lane], pd);
        }
        h = fmaxf(h, 0.f);
        float m = wave_reduce_sum(h * w2[lane]) + b2[0];
        // stable softplus = max(x,0) + log1p(exp(-|x|))
        m = fmaxf(m, 0.f) + log1pf(expf(-fabsf(m)));
        float phi = SQRT_2_OVER_R * cosf(pd);
        acc = fmaf(phi, m, acc);
    }

    __shared__ float s[4][RF];
    s[wave][lane] = acc;
    __syncthreads();
    if (wave == 0) {
        float v = s[0][lane] + s[1][lane] + s[2][lane] + s[3][lane];
        atomicAdd(&phi_sum[b * RF + lane], v);
    }
}

// Pass 2: grav[b,t] = STRENGTH * sum_r phi[b,t,r] * phi_sum[b,r]
// (phi recomputed — cheaper than storing 8 MiB)
__global__ __launch_bounds__(256) void gravity_pass2(
        const float* __restrict__ coords,
        const float* __restrict__ Wr,
        const float* __restrict__ br,
        const float* __restrict__ phi_sum,
        float* __restrict__ grav,           // [B*T]
        int total, int T) {
    const int lane  = threadIdx.x & 63;
    const int gwave = (int)((blockIdx.x * (size_t)blockDim.x + threadIdx.x) >> 6);
    if (gwave >= total) return;
    const int b = gwave / T;

    const float* cptr = coords + (size_t)gwave * DM;
    float c  = cptr[lane];
    float pd = br[lane];
    #pragma unroll
    for (int k = 0; k < DM; ++k) {
        float ck = __shfl(c, k, 64);
        pd = fmaf(ck, Wr[k * RF + lane], pd);
    }
    float phi = SQRT_2_OVER_R * cosf(pd);
    float v = wave_reduce_sum(phi * phi_sum[b * RF + lane]);
    if (lane == 0) grav[gwave] = STRENGTH * v;
}

// Pass 3: out = G, plus grav[token] on the diagonal. Pure HBM streaming.
// 1024 float4 per token (D*D/4); 16 float4 per row of D=64.
__global__ __launch_bounds__(256) void gravity_pass3(
        const float4* __restrict__ G4,
        const float* __restrict__ grav,
        float4* __restrict__ out4,
        size_t n4) {
    size_t idx    = blockIdx.x * (size_t)blockDim.x + threadIdx.x;
    size_t stride = (size_t)gridDim.x * blockDim.x;
    for (; idx < n4; idx += stride) {
        float4 v = G4[idx];
        int token  = (int)(idx >> 10);
        int within = (int)(idx & 1023);
        int i  = within >> 4;
        int j0 = (within & 15) << 2;
        int d  = i - j0;
        if ((unsigned)d < 4u) {
            float g = grav[token];
            if      (d == 0) v.x += g;
            else if (d == 1) v.y += g;
            else if (d == 2) v.z += g;
            else             v.w += g;
        }
        out4[idx] = v;
    }
}

extern "C" void kernel_launch(void* const* d_in, const int* in_sizes, int n_in,
                              void* d_out, int out_size, void* d_ws, size_t ws_size,
                              hipStream_t stream) {
    const float* G      = (const float*)d_in[0];
    const float* coords = (const float*)d_in[1];
    const float* w1     = (const float*)d_in[2];
    const float* b1     = (const float*)d_in[3];
    const float* w2     = (const float*)d_in[4];
    const float* b2     = (const float*)d_in[5];
    const float* Wr     = (const float*)d_in[6];
    const float* br     = (const float*)d_in[7];
    float* out          = (float*)d_out;

    const int BT = in_sizes[1] / DM;        // B*T
    const int B  = NBATCH;
    const int T  = BT / B;

    float* phi_sum = (float*)d_ws;                    // B*R floats = 2 KiB
    float* grav    = (float*)d_ws + B * RF;           // B*T floats = 128 KiB

    hipMemsetAsync(d_ws, 0, (size_t)B * RF * sizeof(float), stream);

    // Pass 1: 64 blocks/batch x 8 batches, 4 waves/block -> 16 tokens/wave
    dim3 g1(64, B);
    gravity_pass1<<<g1, 256, 0, stream>>>(coords, w1, b1, w2, b2, Wr, br,
                                          phi_sum, T);

    // Pass 2: one wave per token
    int blocks2 = (BT + 3) / 4;
    gravity_pass2<<<blocks2, 256, 0, stream>>>(coords, Wr, br, phi_sum, grav,
                                               BT, T);

    // Pass 3: streaming copy + diagonal add
    size_t n4 = (size_t)BT * DM * DM / 4;
    gravity_pass3<<<8192, 256, 0, stream>>>((const float4*)G, grav,
                                            (float4*)out, n4);
}